// Round 1
// baseline (500.552 us; speedup 1.0000x reference)
//
#include <hip/hip_runtime.h>

#define CONT_F 13
#define CATE_F 26
#define FF 39
#define DD 40
#define NCOMB 741
#define BB 2048
#define SUB0 40
#define SUB1 5
#define HH 100
#define K0 1560          // FF*DD, e-part of fc0 input
#define NPART 16

// ---------------------------------------------------------------- build e
// e[b][f][d] = f<13 ? emb[f][d]*conts[b][f] : emb[cates[b][f-13]][d]
__global__ __launch_bounds__(256) void build_e_kernel(
    const float* __restrict__ conts, const int* __restrict__ cates,
    const float* __restrict__ emb, float* __restrict__ e)
{
    const int idx = blockIdx.x * 256 + threadIdx.x;   // over BB*FF*10 float4s
    const int d4 = idx % 10;
    const int f  = (idx / 10) % FF;
    const int b  = idx / (10 * FF);
    float4 val;
    if (f < CONT_F) {
        const float4 em = ((const float4*)(emb + f * DD))[d4];
        const float cv  = conts[b * CONT_F + f];
        val = make_float4(em.x * cv, em.y * cv, em.z * cv, em.w * cv);
    } else {
        const int tok = cates[b * CATE_F + (f - CONT_F)];
        val = ((const float4*)(emb + (size_t)tok * DD))[d4];
    }
    ((float4*)e)[idx] = val;
}

// ---------------------------------------------------------------- subnet
// per (comb c, 256-row tile): z_in=[p,q,p*q] (120) -> w0 (120x40) +b0 -> LN
// -> relu -> w1 (40x5) +b1 -> LN -> relu -> z2[(c,b,j)]
__global__ __launch_bounds__(256) void subnet_kernel(
    const float* __restrict__ e,  const float* __restrict__ w0,
    const float* __restrict__ b0, const float* __restrict__ sln0w,
    const float* __restrict__ sln0b, const float* __restrict__ w1,
    const float* __restrict__ b1, const float* __restrict__ sln1w,
    const float* __restrict__ sln1b, float* __restrict__ z2)
{
    const int c   = blockIdx.x;
    const int row = blockIdx.y * 256 + threadIdx.x;

    // unrank upper-triangle pair index c -> (r,s), block-uniform scalar loop
    int r = 0, rem = c;
    while (rem >= FF - 1 - r) { rem -= FF - 1 - r; ++r; }
    const int s = r + 1 + rem;

    const float4* pr = (const float4*)(e + (size_t)row * K0 + r * DD);
    const float4* qr = (const float4*)(e + (size_t)row * K0 + s * DD);
    const float*  wc = w0 + c * (3 * DD * SUB0);   // (120,40) row-major
    const float*  bc = b0 + c * SUB0;

    float acc[SUB0];
    #pragma unroll
    for (int o = 0; o < SUB0; ++o) acc[o] = bc[o];

    for (int d4 = 0; d4 < DD / 4; ++d4) {          // 10 iters, body unrolled x4
        const float4 pv4 = pr[d4];
        const float4 qv4 = qr[d4];
        const float pvs[4] = {pv4.x, pv4.y, pv4.z, pv4.w};
        const float qvs[4] = {qv4.x, qv4.y, qv4.z, qv4.w};
        #pragma unroll
        for (int dd = 0; dd < 4; ++dd) {
            const int d = d4 * 4 + dd;
            const float pv = pvs[dd], qv = qvs[dd], pq = pv * qv;
            const float* wA = wc + d * SUB0;       // rows d, 40+d, 80+d
            #pragma unroll
            for (int o = 0; o < SUB0; ++o) {
                float a = acc[o];
                a = fmaf(wA[o],        pv, a);
                a = fmaf(wA[1600 + o], qv, a);
                a = fmaf(wA[3200 + o], pq, a);
                acc[o] = a;
            }
        }
    }

    // LayerNorm(40) + relu, all in registers
    float m = 0.f;
    #pragma unroll
    for (int o = 0; o < SUB0; ++o) m += acc[o];
    m *= (1.f / SUB0);
    float v = 0.f;
    #pragma unroll
    for (int o = 0; o < SUB0; ++o) { const float dl = acc[o] - m; v += dl * dl; }
    v *= (1.f / SUB0);
    const float inv = rsqrtf(v + 1e-5f);
    float h[SUB0];
    #pragma unroll
    for (int o = 0; o < SUB0; ++o) {
        const float t = (acc[o] - m) * inv * sln0w[o] + sln0b[o];
        h[o] = t > 0.f ? t : 0.f;
    }

    // 40 -> 5
    const float* w1c = w1 + c * (SUB0 * SUB1);
    float a2[SUB1];
    #pragma unroll
    for (int j = 0; j < SUB1; ++j) a2[j] = b1[c * SUB1 + j];
    #pragma unroll
    for (int k = 0; k < SUB0; ++k) {
        #pragma unroll
        for (int j = 0; j < SUB1; ++j)
            a2[j] = fmaf(w1c[k * SUB1 + j], h[k], a2[j]);
    }

    // LayerNorm(5) + relu
    float m2 = 0.f;
    #pragma unroll
    for (int j = 0; j < SUB1; ++j) m2 += a2[j];
    m2 *= (1.f / SUB1);
    float v2 = 0.f;
    #pragma unroll
    for (int j = 0; j < SUB1; ++j) { const float dl = a2[j] - m2; v2 += dl * dl; }
    v2 *= (1.f / SUB1);
    const float inv2 = rsqrtf(v2 + 1e-5f);

    float* zo = z2 + ((size_t)c * BB + row) * SUB1;   // layout (COMB, B, 5)
    #pragma unroll
    for (int j = 0; j < SUB1; ++j) {
        const float t = (a2[j] - m2) * inv2 * sln1w[j] + sln1b[j];
        zo[j] = t > 0.f ? t : 0.f;
    }
}

// ---------------------------------------------------------------- fc0 (K-chunked, deterministic partials)
// X = [e_flat (1560) | z (741*5)]; partial[kc][row][h] = sum over chunk kc.
// kc 0..3: e-part, 390 k each. kc 4..15: comb chunks of 62 (last 59).
__global__ __launch_bounds__(256) void fc0_partial_kernel(
    const float* __restrict__ e, const float* __restrict__ z2,
    const float* __restrict__ w, float* __restrict__ partial)
{
    const int rt   = blockIdx.x;            // 0..31, 64 rows each
    const int kc   = blockIdx.y;            // 0..15
    const int rloc = threadIdx.x & 63;
    const int ogrp = threadIdx.x >> 6;      // 0..3 -> 25 outputs each (wave-uniform)
    const int row  = rt * 64 + rloc;
    const int ob   = ogrp * 25;

    float acc[25];
    #pragma unroll
    for (int j = 0; j < 25; ++j) acc[j] = 0.f;

    if (kc < 4) {
        const int kbase = kc * 390;
        const float* xr = e + (size_t)row * K0 + kbase;
        const float* wr = w + (size_t)kbase * HH + ob;
        for (int i = 0; i < 390; ++i) {
            const float xv = xr[i];
            const float* wk = wr + (size_t)i * HH;
            #pragma unroll
            for (int j = 0; j < 25; ++j) acc[j] = fmaf(wk[j], xv, acc[j]);
        }
    } else {
        const int c0 = (kc - 4) * 62;
        const int c1 = (c0 + 62 < NCOMB) ? c0 + 62 : NCOMB;
        for (int c = c0; c < c1; ++c) {
            const float* zr = z2 + ((size_t)c * BB + row) * SUB1;
            const float* wk = w + (size_t)(K0 + c * SUB1) * HH + ob;
            #pragma unroll
            for (int j5 = 0; j5 < SUB1; ++j5) {
                const float xv = zr[j5];
                #pragma unroll
                for (int j = 0; j < 25; ++j)
                    acc[j] = fmaf(wk[j5 * HH + j], xv, acc[j]);
            }
        }
    }
    float* po = partial + ((size_t)kc * BB + row) * HH + ob;
    #pragma unroll
    for (int j = 0; j < 25; ++j) po[j] = acc[j];
}

// ---------------------------------------------------------------- fc0 reduce + bias + LN + relu
// one wave per row; lane holds elems {lane, lane+64(<100)}
__global__ __launch_bounds__(256) void fc0_reduce_kernel(
    const float* __restrict__ partial, const float* __restrict__ fc0b,
    const float* __restrict__ ln0w, const float* __restrict__ ln0b,
    float* __restrict__ X1)
{
    const int row  = (blockIdx.x * 256 + threadIdx.x) >> 6;
    const int lane = threadIdx.x & 63;
    float s0 = fc0b[lane];
    float s1 = (lane < 36) ? fc0b[64 + lane] : 0.f;
    #pragma unroll
    for (int p = 0; p < NPART; ++p) {
        const float* pr = partial + ((size_t)p * BB + row) * HH;
        s0 += pr[lane];
        if (lane < 36) s1 += pr[64 + lane];
    }
    float sum = s0 + ((lane < 36) ? s1 : 0.f);
    #pragma unroll
    for (int off = 32; off; off >>= 1) sum += __shfl_xor(sum, off, 64);
    const float m  = sum * 0.01f;
    const float d0 = s0 - m;
    const float d1 = (lane < 36) ? (s1 - m) : 0.f;
    float vs = d0 * d0 + d1 * d1;
    #pragma unroll
    for (int off = 32; off; off >>= 1) vs += __shfl_xor(vs, off, 64);
    const float inv = rsqrtf(vs * 0.01f + 1e-5f);
    float x0 = d0 * inv * ln0w[lane] + ln0b[lane];
    X1[(size_t)row * HH + lane] = x0 > 0.f ? x0 : 0.f;
    if (lane < 36) {
        float x1 = d1 * inv * ln0w[64 + lane] + ln0b[64 + lane];
        X1[(size_t)row * HH + 64 + lane] = x1 > 0.f ? x1 : 0.f;
    }
}

// ---------------------------------------------------------------- fc1 + LN + out + sigmoid
__global__ __launch_bounds__(256) void head_kernel(
    const float* __restrict__ X1, const float* __restrict__ fc1w,
    const float* __restrict__ fc1b, const float* __restrict__ ln1w,
    const float* __restrict__ ln1b, const float* __restrict__ outw,
    const float* __restrict__ outb, float* __restrict__ out)
{
    const int row  = (blockIdx.x * 256 + threadIdx.x) >> 6;
    const int lane = threadIdx.x & 63;
    const float* xr = X1 + (size_t)row * HH;
    float a0 = fc1b[lane];
    float a1 = (lane < 36) ? fc1b[64 + lane] : 0.f;
    for (int k = 0; k < HH; ++k) {
        const float xv = xr[k];                      // wave-uniform -> s_load
        a0 = fmaf(fc1w[k * HH + lane], xv, a0);
        if (lane < 36) a1 = fmaf(fc1w[k * HH + 64 + lane], xv, a1);
    }
    float sum = a0 + ((lane < 36) ? a1 : 0.f);
    #pragma unroll
    for (int off = 32; off; off >>= 1) sum += __shfl_xor(sum, off, 64);
    const float m  = sum * 0.01f;
    const float d0 = a0 - m;
    const float d1 = (lane < 36) ? (a1 - m) : 0.f;
    float vs = d0 * d0 + d1 * d1;
    #pragma unroll
    for (int off = 32; off; off >>= 1) vs += __shfl_xor(vs, off, 64);
    const float inv = rsqrtf(vs * 0.01f + 1e-5f);
    float x0 = d0 * inv * ln1w[lane] + ln1b[lane];
    x0 = x0 > 0.f ? x0 : 0.f;
    float t = x0 * outw[lane];
    if (lane < 36) {
        float x1 = d1 * inv * ln1w[64 + lane] + ln1b[64 + lane];
        x1 = x1 > 0.f ? x1 : 0.f;
        t = fmaf(x1, outw[64 + lane], t);
    }
    #pragma unroll
    for (int off = 32; off; off >>= 1) t += __shfl_xor(t, off, 64);
    if (lane == 0) {
        const float z = t + outb[0];
        out[row] = 1.f / (1.f + expf(-z));
    }
}

// ---------------------------------------------------------------- launch
extern "C" void kernel_launch(void* const* d_in, const int* in_sizes, int n_in,
                              void* d_out, int out_size, void* d_ws, size_t ws_size,
                              hipStream_t stream)
{
    const float* conts = (const float*)d_in[0];
    const int*   cates = (const int*)d_in[1];
    // d_in[2] = combs placeholder, unused
    const float* emb   = (const float*)d_in[3];
    const float* w0    = (const float*)d_in[4];
    const float* b0    = (const float*)d_in[5];
    const float* sln0w = (const float*)d_in[6];
    const float* sln0b = (const float*)d_in[7];
    const float* w1    = (const float*)d_in[8];
    const float* b1    = (const float*)d_in[9];
    const float* sln1w = (const float*)d_in[10];
    const float* sln1b = (const float*)d_in[11];
    const float* fc0w  = (const float*)d_in[12];
    const float* fc0b  = (const float*)d_in[13];
    const float* ln0w  = (const float*)d_in[14];
    const float* ln0b  = (const float*)d_in[15];
    const float* fc1w  = (const float*)d_in[16];
    const float* fc1b  = (const float*)d_in[17];
    const float* ln1w  = (const float*)d_in[18];
    const float* ln1b  = (const float*)d_in[19];
    const float* outw  = (const float*)d_in[20];
    const float* outb  = (const float*)d_in[21];
    float* out = (float*)d_out;

    // workspace layout (fp32): e | z2 | partial | X1  = ~57 MB
    float* e       = (float*)d_ws;
    float* z2      = e + (size_t)BB * K0;                 // 3,194,880
    float* partial = z2 + (size_t)NCOMB * BB * SUB1;      // +7,587,840
    float* X1      = partial + (size_t)NPART * BB * HH;   // +3,276,800

    build_e_kernel<<<(BB * FF * 10) / 256, 256, 0, stream>>>(conts, cates, emb, e);
    subnet_kernel<<<dim3(NCOMB, BB / 256), 256, 0, stream>>>(
        e, w0, b0, sln0w, sln0b, w1, b1, sln1w, sln1b, z2);
    fc0_partial_kernel<<<dim3(BB / 64, NPART), 256, 0, stream>>>(e, z2, fc0w, partial);
    fc0_reduce_kernel<<<BB / 4, 256, 0, stream>>>(partial, fc0b, ln0w, ln0b, X1);
    head_kernel<<<BB / 4, 256, 0, stream>>>(X1, fc1w, fc1b, ln1w, ln1b, outw, outb, out);
}

// Round 2
// 487.818 us; speedup vs baseline: 1.0261x; 1.0261x over previous
//
#include <hip/hip_runtime.h>

#define CONT_F 13
#define CATE_F 26
#define FF 39
#define DD 40
#define NCOMB 741
#define BB 2048
#define SUB0 40
#define SUB1 5
#define HH 100
#define K0 1560            // FF*DD, e-part of fc0 input
#define KTOT 5265          // K0 + NCOMB*SUB1
#define XSTRIDE 5280       // padded row stride (pad cols never read)
#define NPART 15           // 15 chunks of 351 == 5265 exactly
#define KCH 351
#define CPX 93             // combs per XCD (93*8 = 744, 3 dummies)

// ---------------------------------------------------------------- build e -> X[:, 0:1560]
__global__ __launch_bounds__(256) void build_e_kernel(
    const float* __restrict__ conts, const int* __restrict__ cates,
    const float* __restrict__ emb, float* __restrict__ X)
{
    const int idx = blockIdx.x * 256 + threadIdx.x;   // over BB*FF*10 float4s
    const int d4 = idx % 10;
    const int f  = (idx / 10) % FF;
    const int b  = idx / (10 * FF);
    float4 val;
    if (f < CONT_F) {
        const float4 em = ((const float4*)(emb + f * DD))[d4];
        const float cv  = conts[b * CONT_F + f];
        val = make_float4(em.x * cv, em.y * cv, em.z * cv, em.w * cv);
    } else {
        const int tok = cates[b * CATE_F + (f - CONT_F)];
        val = ((const float4*)(emb + (size_t)tok * DD))[d4];
    }
    ((float4*)(X + (size_t)b * XSTRIDE))[f * 10 + d4] = val;
}

// ---------------------------------------------------------------- subnet
// XCD-aware: wgid&7 = XCD, XCD k owns combs [93k, 93k+93) x all 8 row-tiles,
// comb-fastest => per-XCD hot set = 1.8MB weights + 1.6MB e-tile < 4MB L2.
__global__ __launch_bounds__(256) void subnet_kernel(
    const float* __restrict__ X_in, const float* __restrict__ w0,
    const float* __restrict__ b0, const float* __restrict__ sln0w,
    const float* __restrict__ sln0b, const float* __restrict__ w1,
    const float* __restrict__ b1, const float* __restrict__ sln1w,
    const float* __restrict__ sln1b, float* __restrict__ X_out)
{
    const int wgid   = blockIdx.x;
    const int xcd    = wgid & 7;
    const int within = wgid >> 3;            // 0..743, comb-fastest
    const int c_loc  = within % CPX;
    const int tl     = within / CPX;         // 0..7 row-tile
    const int c      = xcd * CPX + c_loc;
    if (c >= NCOMB) return;                  // 3 dummy blocks on xcd 7
    const int row = tl * 256 + threadIdx.x;

    // unrank upper-triangle pair index c -> (r,s), block-uniform scalar loop
    int r = 0, rem = c;
    while (rem >= FF - 1 - r) { rem -= FF - 1 - r; ++r; }
    const int s = r + 1 + rem;

    const float4* pr = (const float4*)(X_in + (size_t)row * XSTRIDE + r * DD);
    const float4* qr = (const float4*)(X_in + (size_t)row * XSTRIDE + s * DD);
    const float*  wc = w0 + c * (3 * DD * SUB0);   // (120,40) row-major
    const float*  bc = b0 + c * SUB0;

    float acc[SUB0];
    #pragma unroll
    for (int o = 0; o < SUB0; ++o) acc[o] = bc[o];

    for (int d4 = 0; d4 < DD / 4; ++d4) {
        const float4 pv4 = pr[d4];
        const float4 qv4 = qr[d4];
        #define DO_D(comp, dd) { \
            const float pv = pv4.comp, qv = qv4.comp, pq = pv * qv; \
            const float* wA = wc + (d4 * 4 + dd) * SUB0; \
            _Pragma("unroll") \
            for (int o = 0; o < SUB0; ++o) { \
                float a = acc[o]; \
                a = fmaf(wA[o],        pv, a); \
                a = fmaf(wA[1600 + o], qv, a); \
                a = fmaf(wA[3200 + o], pq, a); \
                acc[o] = a; } }
        DO_D(x, 0) DO_D(y, 1) DO_D(z, 2) DO_D(w, 3)
        #undef DO_D
    }

    // LayerNorm(40) + relu, in registers
    float m = 0.f;
    #pragma unroll
    for (int o = 0; o < SUB0; ++o) m += acc[o];
    m *= (1.f / SUB0);
    float v = 0.f;
    #pragma unroll
    for (int o = 0; o < SUB0; ++o) { const float dl = acc[o] - m; v += dl * dl; }
    v *= (1.f / SUB0);
    const float inv = rsqrtf(v + 1e-5f);
    float h[SUB0];
    #pragma unroll
    for (int o = 0; o < SUB0; ++o) {
        const float t = (acc[o] - m) * inv * sln0w[o] + sln0b[o];
        h[o] = t > 0.f ? t : 0.f;
    }

    // 40 -> 5
    const float* w1c = w1 + c * (SUB0 * SUB1);
    float a2[SUB1];
    #pragma unroll
    for (int j = 0; j < SUB1; ++j) a2[j] = b1[c * SUB1 + j];
    #pragma unroll
    for (int k = 0; k < SUB0; ++k) {
        #pragma unroll
        for (int j = 0; j < SUB1; ++j)
            a2[j] = fmaf(w1c[k * SUB1 + j], h[k], a2[j]);
    }

    // LayerNorm(5) + relu -> X[:, 1560 + c*5 ...]
    float m2 = 0.f;
    #pragma unroll
    for (int j = 0; j < SUB1; ++j) m2 += a2[j];
    m2 *= (1.f / SUB1);
    float v2 = 0.f;
    #pragma unroll
    for (int j = 0; j < SUB1; ++j) { const float dl = a2[j] - m2; v2 += dl * dl; }
    v2 *= (1.f / SUB1);
    const float inv2 = rsqrtf(v2 + 1e-5f);

    float* zo = X_out + (size_t)row * XSTRIDE + K0 + c * SUB1;
    #pragma unroll
    for (int j = 0; j < SUB1; ++j) {
        const float t = (a2[j] - m2) * inv2 * sln1w[j] + sln1b[j];
        zo[j] = t > 0.f ? t : 0.f;
    }
}

// ---------------------------------------------------------------- fc0 partials
// 15 exact K-chunks of 351 over the contiguous X row (no pad reads).
__global__ __launch_bounds__(256) void fc0_partial_kernel(
    const float* __restrict__ X, const float* __restrict__ w,
    float* __restrict__ partial)
{
    const int rt   = blockIdx.x;            // 0..31, 64 rows each
    const int kc   = blockIdx.y;            // 0..14
    const int rloc = threadIdx.x & 63;
    const int ogrp = threadIdx.x >> 6;      // wave-uniform, 25 outputs each
    const int row  = rt * 64 + rloc;
    const int ob   = ogrp * 25;

    const float* xr = X + (size_t)row * XSTRIDE + kc * KCH;
    const float* wr = w + (size_t)(kc * KCH) * HH + ob;

    float acc[25];
    #pragma unroll
    for (int j = 0; j < 25; ++j) acc[j] = 0.f;

    for (int i = 0; i < KCH; ++i) {
        const float xv = xr[i];
        const float* wk = wr + (size_t)i * HH;
        #pragma unroll
        for (int j = 0; j < 25; ++j) acc[j] = fmaf(wk[j], xv, acc[j]);
    }
    float* po = partial + ((size_t)kc * BB + row) * HH + ob;
    #pragma unroll
    for (int j = 0; j < 25; ++j) po[j] = acc[j];
}

// ---------------------------------------------------------------- fused: fc0 reduce + LN + relu + fc1 + LN + out + sigmoid
// one wave per row; lane holds elems {lane, 64+lane(<100)}; X1 row via LDS
// (written and read by the SAME wave -> no barrier needed).
__global__ __launch_bounds__(256) void fc0rh_kernel(
    const float* __restrict__ partial, const float* __restrict__ fc0b,
    const float* __restrict__ ln0w, const float* __restrict__ ln0b,
    const float* __restrict__ fc1w, const float* __restrict__ fc1b,
    const float* __restrict__ ln1w, const float* __restrict__ ln1b,
    const float* __restrict__ outw, const float* __restrict__ outb,
    float* __restrict__ out)
{
    __shared__ float xs[4][104];
    const int wl   = threadIdx.x >> 6;
    const int lane = threadIdx.x & 63;
    const int row  = blockIdx.x * 4 + wl;

    float s0 = fc0b[lane];
    float s1 = (lane < 36) ? fc0b[64 + lane] : 0.f;
    #pragma unroll
    for (int p = 0; p < NPART; ++p) {
        const float* pr = partial + ((size_t)p * BB + row) * HH;
        s0 += pr[lane];
        if (lane < 36) s1 += pr[64 + lane];
    }
    float sum = s0 + ((lane < 36) ? s1 : 0.f);
    #pragma unroll
    for (int off = 32; off; off >>= 1) sum += __shfl_xor(sum, off, 64);
    float m  = sum * 0.01f;
    float d0 = s0 - m;
    float d1 = (lane < 36) ? (s1 - m) : 0.f;
    float vs = d0 * d0 + d1 * d1;
    #pragma unroll
    for (int off = 32; off; off >>= 1) vs += __shfl_xor(vs, off, 64);
    float inv = rsqrtf(vs * 0.01f + 1e-5f);
    {
        float x0 = d0 * inv * ln0w[lane] + ln0b[lane];
        xs[wl][lane] = x0 > 0.f ? x0 : 0.f;
        if (lane < 36) {
            float x1 = d1 * inv * ln0w[64 + lane] + ln0b[64 + lane];
            xs[wl][64 + lane] = x1 > 0.f ? x1 : 0.f;
        }
    }

    // fc1 (100x100) from LDS row (same-wave data, lgkmcnt ordering suffices)
    float a0 = fc1b[lane];
    float a1 = (lane < 36) ? fc1b[64 + lane] : 0.f;
    for (int k = 0; k < HH; ++k) {
        const float xv = xs[wl][k];
        a0 = fmaf(fc1w[k * HH + lane], xv, a0);
        if (lane < 36) a1 = fmaf(fc1w[k * HH + 64 + lane], xv, a1);
    }
    sum = a0 + ((lane < 36) ? a1 : 0.f);
    #pragma unroll
    for (int off = 32; off; off >>= 1) sum += __shfl_xor(sum, off, 64);
    m  = sum * 0.01f;
    d0 = a0 - m;
    d1 = (lane < 36) ? (a1 - m) : 0.f;
    vs = d0 * d0 + d1 * d1;
    #pragma unroll
    for (int off = 32; off; off >>= 1) vs += __shfl_xor(vs, off, 64);
    inv = rsqrtf(vs * 0.01f + 1e-5f);

    float x0 = d0 * inv * ln1w[lane] + ln1b[lane];
    x0 = x0 > 0.f ? x0 : 0.f;
    float t = x0 * outw[lane];
    if (lane < 36) {
        float x1 = d1 * inv * ln1w[64 + lane] + ln1b[64 + lane];
        x1 = x1 > 0.f ? x1 : 0.f;
        t = fmaf(x1, outw[64 + lane], t);
    }
    #pragma unroll
    for (int off = 32; off; off >>= 1) t += __shfl_xor(t, off, 64);
    if (lane == 0) {
        const float z = t + outb[0];
        out[row] = 1.f / (1.f + expf(-z));
    }
}

// ---------------------------------------------------------------- launch
extern "C" void kernel_launch(void* const* d_in, const int* in_sizes, int n_in,
                              void* d_out, int out_size, void* d_ws, size_t ws_size,
                              hipStream_t stream)
{
    const float* conts = (const float*)d_in[0];
    const int*   cates = (const int*)d_in[1];
    // d_in[2] = combs placeholder, unused
    const float* emb   = (const float*)d_in[3];
    const float* w0    = (const float*)d_in[4];
    const float* b0    = (const float*)d_in[5];
    const float* sln0w = (const float*)d_in[6];
    const float* sln0b = (const float*)d_in[7];
    const float* w1    = (const float*)d_in[8];
    const float* b1    = (const float*)d_in[9];
    const float* sln1w = (const float*)d_in[10];
    const float* sln1b = (const float*)d_in[11];
    const float* fc0w  = (const float*)d_in[12];
    const float* fc0b  = (const float*)d_in[13];
    const float* ln0w  = (const float*)d_in[14];
    const float* ln0b  = (const float*)d_in[15];
    const float* fc1w  = (const float*)d_in[16];
    const float* fc1b  = (const float*)d_in[17];
    const float* ln1w  = (const float*)d_in[18];
    const float* ln1b  = (const float*)d_in[19];
    const float* outw  = (const float*)d_in[20];
    const float* outb  = (const float*)d_in[21];
    float* out = (float*)d_out;

    // workspace: X (2048x5280 f32, 43.3MB) | partial (15x2048x100 f32, 12.3MB)
    float* X       = (float*)d_ws;
    float* partial = X + (size_t)BB * XSTRIDE;

    build_e_kernel<<<(BB * FF * 10) / 256, 256, 0, stream>>>(conts, cates, emb, X);
    subnet_kernel<<<CPX * 8 * 8, 256, 0, stream>>>(
        X, w0, b0, sln0w, sln0b, w1, b1, sln1w, sln1b, X);
    fc0_partial_kernel<<<dim3(BB / 64, NPART), 256, 0, stream>>>(X, fc0w, partial);
    fc0rh_kernel<<<BB / 4, 256, 0, stream>>>(
        partial, fc0b, ln0w, ln0b, fc1w, fc1b, ln1w, ln1b, outw, outb, out);
}

// Round 4
// 392.467 us; speedup vs baseline: 1.2754x; 1.2430x over previous
//
#include <hip/hip_runtime.h>

#define CONT_F 13
#define CATE_F 26
#define FF 39
#define DD 40
#define NCOMB 741
#define BB 2048
#define SUB0 40
#define SUB1 5
#define HH 100
#define K0 1560            // FF*DD rows of XT (e-part)
#define KTOT 5265          // K0 + NCOMB*SUB1 rows of XT
#define NPART 15
#define KCH 351            // 15*351 = 5265 exactly
#define CPX 93             // combs per XCD

// XT layout: [KTOT][BB] floats — k-major, batch contiguous.

// ---------------------------------------------------------------- build e -> XT rows [0,1560)
// block = (feature f, 256-batch tile); lanes span b => all stores coalesced.
__global__ __launch_bounds__(256) void build_eT_kernel(
    const float* __restrict__ conts, const int* __restrict__ cates,
    const float* __restrict__ emb, float* __restrict__ XT)
{
    const int f = blockIdx.x;
    const int b = blockIdx.y * 256 + threadIdx.x;
    float* xo = XT + (size_t)(f * DD) * BB + b;
    if (f < CONT_F) {
        const float cv = conts[b * CONT_F + f];
        const float* em = emb + f * DD;          // f uniform -> s_load row
        #pragma unroll
        for (int d = 0; d < DD; ++d)
            xo[(size_t)d * BB] = em[d] * cv;
    } else {
        const int tok = cates[b * CATE_F + (f - CONT_F)];
        const float4* er = (const float4*)(emb + (size_t)tok * DD);
        #pragma unroll
        for (int d4 = 0; d4 < DD / 4; ++d4) {
            const float4 v = er[d4];
            xo[(size_t)(d4 * 4 + 0) * BB] = v.x;
            xo[(size_t)(d4 * 4 + 1) * BB] = v.y;
            xo[(size_t)(d4 * 4 + 2) * BB] = v.z;
            xo[(size_t)(d4 * 4 + 3) * BB] = v.w;
        }
    }
}

// ---------------------------------------------------------------- subnet
// 128 threads, R=2 batch rows per thread (float2), block covers 256 rows.
// XCD-partitioned: xcd owns 93 combs; tile-slow order => per-XCD hot set
// = 1.8MB weights + 1.6MB e-tile < 4MB L2.
__global__ __launch_bounds__(128) void subnetT_kernel(
    const float* __restrict__ XT, const float* __restrict__ w0,
    const float* __restrict__ b0, const float* __restrict__ sln0w,
    const float* __restrict__ sln0b, const float* __restrict__ w1,
    const float* __restrict__ b1, const float* __restrict__ sln1w,
    const float* __restrict__ sln1b, float* __restrict__ XTz)
{
    const int wgid   = blockIdx.x;
    const int xcd    = wgid & 7;
    const int within = wgid >> 3;           // 0..743: tl slow, comb fast
    const int c_loc  = within % CPX;
    const int tl     = within / CPX;        // 0..7 (256-row tiles)
    const int c      = xcd * CPX + c_loc;
    if (c >= NCOMB) return;
    const int col = tl * 256 + threadIdx.x * 2;   // 2 consecutive batch rows

    // unrank c -> (r,s)
    int r = 0, rem = c;
    while (rem >= FF - 1 - r) { rem -= FF - 1 - r; ++r; }
    const int s = r + 1 + rem;

    const float* Pr = XT + (size_t)(r * DD) * BB + col;
    const float* Qr = XT + (size_t)(s * DD) * BB + col;
    const float* wc = w0 + c * (3 * DD * SUB0);
    const float* bc = b0 + c * SUB0;

    float acc0[SUB0], acc1[SUB0];
    #pragma unroll
    for (int o = 0; o < SUB0; ++o) { acc0[o] = bc[o]; acc1[o] = bc[o]; }

    // unroll 4 (not full): keeps hot loop ~8KB (icache 32KB) with 4-deep
    // s_load pipeline; full unroll would be ~80KB and thrash icache.
    #pragma unroll 4
    for (int d = 0; d < DD; ++d) {
        const float2 pv = *(const float2*)(Pr + (size_t)d * BB);
        const float2 qv = *(const float2*)(Qr + (size_t)d * BB);
        const float pq0 = pv.x * qv.x, pq1 = pv.y * qv.y;
        const float* wA = wc + d * SUB0;
        #pragma unroll
        for (int o = 0; o < SUB0; ++o) {
            const float wp = wA[o], wq = wA[1600 + o], wx = wA[3200 + o];
            float a0 = acc0[o], a1 = acc1[o];
            a0 = fmaf(wp, pv.x, a0);  a1 = fmaf(wp, pv.y, a1);
            a0 = fmaf(wq, qv.x, a0);  a1 = fmaf(wq, qv.y, a1);
            a0 = fmaf(wx, pq0, a0);   a1 = fmaf(wx, pq1, a1);
            acc0[o] = a0; acc1[o] = a1;
        }
    }

    // LayerNorm(40) + relu per row, in-place
    #define LN40(acc) { \
        float m = 0.f; \
        _Pragma("unroll") for (int o = 0; o < SUB0; ++o) m += acc[o]; \
        m *= (1.f / SUB0); \
        float v = 0.f; \
        _Pragma("unroll") for (int o = 0; o < SUB0; ++o) { const float dl = acc[o] - m; v += dl * dl; } \
        v *= (1.f / SUB0); \
        const float inv = rsqrtf(v + 1e-5f); \
        _Pragma("unroll") for (int o = 0; o < SUB0; ++o) { \
            const float t = (acc[o] - m) * inv * sln0w[o] + sln0b[o]; \
            acc[o] = t > 0.f ? t : 0.f; } }
    LN40(acc0)
    LN40(acc1)
    #undef LN40

    // 40 -> 5
    const float* w1c = w1 + c * (SUB0 * SUB1);
    float a20[SUB1], a21[SUB1];
    #pragma unroll
    for (int j = 0; j < SUB1; ++j) { a20[j] = b1[c * SUB1 + j]; a21[j] = a20[j]; }
    #pragma unroll
    for (int k = 0; k < SUB0; ++k) {
        #pragma unroll
        for (int j = 0; j < SUB1; ++j) {
            const float wv = w1c[k * SUB1 + j];
            a20[j] = fmaf(wv, acc0[k], a20[j]);
            a21[j] = fmaf(wv, acc1[k], a21[j]);
        }
    }

    // LayerNorm(5) + relu -> XT rows K0 + c*5 + j, coalesced float2 stores
    #define LN5(a2) { \
        float m2 = 0.f; \
        _Pragma("unroll") for (int j = 0; j < SUB1; ++j) m2 += a2[j]; \
        m2 *= (1.f / SUB1); \
        float v2 = 0.f; \
        _Pragma("unroll") for (int j = 0; j < SUB1; ++j) { const float dl = a2[j] - m2; v2 += dl * dl; } \
        v2 *= (1.f / SUB1); \
        const float inv2 = rsqrtf(v2 + 1e-5f); \
        _Pragma("unroll") for (int j = 0; j < SUB1; ++j) \
            a2[j] = fmaxf((a2[j] - m2) * inv2 * sln1w[j] + sln1b[j], 0.f); }
    LN5(a20)
    LN5(a21)
    #undef LN5

    float* zo = XTz + (size_t)(K0 + c * SUB1) * BB + col;
    #pragma unroll
    for (int j = 0; j < SUB1; ++j) {
        float2 st; st.x = a20[j]; st.y = a21[j];
        *(float2*)(zo + (size_t)j * BB) = st;
    }
}

// ---------------------------------------------------------------- fc0 partials
// lane = row (coalesced XT reads); ogrp wave-uniform -> scalar weight loads.
// Output staged in LDS then written coalesced.
__global__ __launch_bounds__(256) void fc0_partialT_kernel(
    const float* __restrict__ XT, const float* __restrict__ w,
    float* __restrict__ partial)
{
    __shared__ float st[64][105];            // pad 105 -> conflict-free
    const int rt   = blockIdx.x;             // 0..31
    const int kc   = blockIdx.y;             // 0..14
    const int rloc = threadIdx.x & 63;
    const int ob   = __builtin_amdgcn_readfirstlane((threadIdx.x >> 6) * 25);
    const int row  = rt * 64 + rloc;

    const float* xr = XT + (size_t)(kc * KCH) * BB + row;
    const float* wr = w + (size_t)(kc * KCH) * HH + ob;

    float acc[25];
    #pragma unroll
    for (int j = 0; j < 25; ++j) acc[j] = 0.f;

    #pragma unroll 3
    for (int i = 0; i < KCH; ++i) {
        const float xv = xr[(size_t)i * BB];           // coalesced across lanes
        const float* wk = wr + (size_t)i * HH;         // wave-uniform -> s_load
        #pragma unroll
        for (int j = 0; j < 25; ++j) acc[j] = fmaf(wk[j], xv, acc[j]);
    }
    #pragma unroll
    for (int j = 0; j < 25; ++j) st[rloc][ob + j] = acc[j];
    __syncthreads();

    // cooperative coalesced write: 64 rows x 100 h
    float* po = partial + ((size_t)kc * BB + rt * 64) * HH;
    #pragma unroll
    for (int k = 0; k < 25; ++k) {
        const int idx = k * 256 + threadIdx.x;
        const int rr = idx / 100, hh = idx % 100;
        po[idx] = st[rr][hh];
    }
}

// ---------------------------------------------------------------- fused fc0-reduce + LN + relu + fc1 + LN + out + sigmoid
__global__ __launch_bounds__(256) void fc0rh_kernel(
    const float* __restrict__ partial, const float* __restrict__ fc0b,
    const float* __restrict__ ln0w, const float* __restrict__ ln0b,
    const float* __restrict__ fc1w, const float* __restrict__ fc1b,
    const float* __restrict__ ln1w, const float* __restrict__ ln1b,
    const float* __restrict__ outw, const float* __restrict__ outb,
    float* __restrict__ out)
{
    __shared__ float xs[4][104];
    const int wl   = threadIdx.x >> 6;
    const int lane = threadIdx.x & 63;
    const int row  = blockIdx.x * 4 + wl;

    float s0 = fc0b[lane];
    float s1 = (lane < 36) ? fc0b[64 + lane] : 0.f;
    #pragma unroll
    for (int p = 0; p < NPART; ++p) {
        const float* pr = partial + ((size_t)p * BB + row) * HH;
        s0 += pr[lane];
        if (lane < 36) s1 += pr[64 + lane];
    }
    float sum = s0 + ((lane < 36) ? s1 : 0.f);
    #pragma unroll
    for (int off = 32; off; off >>= 1) sum += __shfl_xor(sum, off, 64);
    float m  = sum * 0.01f;
    float d0 = s0 - m;
    float d1 = (lane < 36) ? (s1 - m) : 0.f;
    float vs = d0 * d0 + d1 * d1;
    #pragma unroll
    for (int off = 32; off; off >>= 1) vs += __shfl_xor(vs, off, 64);
    float inv = rsqrtf(vs * 0.01f + 1e-5f);
    {
        float x0 = d0 * inv * ln0w[lane] + ln0b[lane];
        xs[wl][lane] = x0 > 0.f ? x0 : 0.f;
        if (lane < 36) {
            float x1 = d1 * inv * ln0w[64 + lane] + ln0b[64 + lane];
            xs[wl][64 + lane] = x1 > 0.f ? x1 : 0.f;
        }
    }

    float a0 = fc1b[lane];
    float a1 = (lane < 36) ? fc1b[64 + lane] : 0.f;
    for (int k = 0; k < HH; ++k) {
        const float xv = xs[wl][k];
        a0 = fmaf(fc1w[k * HH + lane], xv, a0);
        if (lane < 36) a1 = fmaf(fc1w[k * HH + 64 + lane], xv, a1);
    }
    sum = a0 + ((lane < 36) ? a1 : 0.f);
    #pragma unroll
    for (int off = 32; off; off >>= 1) sum += __shfl_xor(sum, off, 64);
    m  = sum * 0.01f;
    d0 = a0 - m;
    d1 = (lane < 36) ? (a1 - m) : 0.f;
    vs = d0 * d0 + d1 * d1;
    #pragma unroll
    for (int off = 32; off; off >>= 1) vs += __shfl_xor(vs, off, 64);
    inv = rsqrtf(vs * 0.01f + 1e-5f);

    float x0 = d0 * inv * ln1w[lane] + ln1b[lane];
    x0 = x0 > 0.f ? x0 : 0.f;
    float t = x0 * outw[lane];
    if (lane < 36) {
        float x1 = d1 * inv * ln1w[64 + lane] + ln1b[64 + lane];
        x1 = x1 > 0.f ? x1 : 0.f;
        t = fmaf(x1, outw[64 + lane], t);
    }
    #pragma unroll
    for (int off = 32; off; off >>= 1) t += __shfl_xor(t, off, 64);
    if (lane == 0) {
        const float z = t + outb[0];
        out[row] = 1.f / (1.f + expf(-z));
    }
}

// ---------------------------------------------------------------- launch
extern "C" void kernel_launch(void* const* d_in, const int* in_sizes, int n_in,
                              void* d_out, int out_size, void* d_ws, size_t ws_size,
                              hipStream_t stream)
{
    const float* conts = (const float*)d_in[0];
    const int*   cates = (const int*)d_in[1];
    const float* emb   = (const float*)d_in[3];
    const float* w0    = (const float*)d_in[4];
    const float* b0    = (const float*)d_in[5];
    const float* sln0w = (const float*)d_in[6];
    const float* sln0b = (const float*)d_in[7];
    const float* w1    = (const float*)d_in[8];
    const float* b1    = (const float*)d_in[9];
    const float* sln1w = (const float*)d_in[10];
    const float* sln1b = (const float*)d_in[11];
    const float* fc0w  = (const float*)d_in[12];
    const float* fc0b  = (const float*)d_in[13];
    const float* ln0w  = (const float*)d_in[14];
    const float* ln0b  = (const float*)d_in[15];
    const float* fc1w  = (const float*)d_in[16];
    const float* fc1b  = (const float*)d_in[17];
    const float* ln1w  = (const float*)d_in[18];
    const float* ln1b  = (const float*)d_in[19];
    const float* outw  = (const float*)d_in[20];
    const float* outb  = (const float*)d_in[21];
    float* out = (float*)d_out;

    // ws: XT (5265x2048 f32 = 43.1MB) | partial (15x2048x100 = 12.3MB) => 55.4MB
    float* XT      = (float*)d_ws;
    float* partial = XT + (size_t)KTOT * BB;

    build_eT_kernel<<<dim3(FF, BB / 256), 256, 0, stream>>>(conts, cates, emb, XT);
    subnetT_kernel<<<8 * CPX * 8, 128, 0, stream>>>(
        XT, w0, b0, sln0w, sln0b, w1, b1, sln1w, sln1b, XT);
    fc0_partialT_kernel<<<dim3(BB / 64, NPART), 256, 0, stream>>>(XT, fc0w, partial);
    fc0rh_kernel<<<BB / 4, 256, 0, stream>>>(
        partial, fc0b, ln0w, ln0b, fc1w, fc1b, ln1w, ln1b, outw, outb, out);
}